// Round 5
// baseline (276.116 us; speedup 1.0000x reference)
//
#include <hip/hip_runtime.h>

// QuantumRNNCell v7: fused, barrier-free, store-tolerant vmcnt pipeline.
//
//   Diagnosis: v3/v4/v5/v6 all cap at ~2.45 TB/s because every loop body is
//   load -> wait -> compute -> store. Loads and stores share vmcnt with
//   in-order retirement on CDNA, so waiting for the newest load drains the
//   previous iteration's store-ack (~1000 cy) every trip. fillBuffer (no
//   loads) hits 6.6 TB/s at 10% occupancy.
//
//   Fix: wave-autonomous fused kernel, NO barriers / LDS. 4096 waves; wave w:
//     - sims rows w + k*4096 (k=0..7), q expvals stay in VGPRs (readlane
//       broadcast at use; q6 never touches memory);
//     - streams its 8-row tile per 64-col4 weight chunk with a 2-deep load
//       rotation where iteration k issues row k+2's load BEFORE row k's
//       store -> every wait-for-load has only YOUNGER stores outstanding ->
//       compiler emits counted vmcnt(N>0), stores never drain the pipe.
//     - chunk-0 weights + first two hx rows issued before the sim phase so
//       ~4 us of sim VALU hides the ramp.
//
// Fixed shape: B = 32768, H = 1024 (256 float4 per row). 1024 blocks x 256.

#define NQ 6

typedef float floatx4 __attribute__((ext_vector_type(4)));

__device__ __forceinline__ float rl(float v, int lane) {
    return __int_as_float(__builtin_amdgcn_readlane(__float_as_int(v), lane));
}

__global__ __launch_bounds__(256, 4) void qrnn_fused_kernel(
    const float* __restrict__ x,     // (B, 6)
    const float* __restrict__ hx,    // (B, H)
    const float* __restrict__ qw,    // (3, 6)
    const float* __restrict__ fc_w,  // (H, 6)
    const float* __restrict__ fc_b,  // (H,)
    float* __restrict__ out)         // (B, H)
{
    const int tid = threadIdx.x;
    const int l   = tid & 63;            // lane = basis state
    const int wv  = tid >> 6;            // wave 0..3
    const int w   = blockIdx.x * 4 + wv; // global wave id, 0..4095
    // this wave's rows: w + k*4096, k = 0..7

    const float4* hx4 = (const float4*)hx;
    const float4* w4  = (const float4*)fc_w;
    const float4* b4  = (const float4*)fc_b;
    floatx4* out4 = (floatx4*)out;

    // ---- early issue: chunk-0 weights + bias + first two hx rows ----
    // (in flight through the whole sim phase; consumed only in the epilogue)
    const int c0 = l;
    const float4 pa0 = w4[c0 * 6 + 0], pa1 = w4[c0 * 6 + 1], pa2 = w4[c0 * 6 + 2];
    const float4 pa3 = w4[c0 * 6 + 3], pa4 = w4[c0 * 6 + 4], pa5 = w4[c0 * 6 + 5];
    const float4 pbv = b4[c0];
    const float4 ph0 = hx4[(size_t)(w + 0 * 4096) * 256 + c0];
    const float4 ph1 = hx4[(size_t)(w + 1 * 4096) * 256 + c0];

    // ---- row-invariant variational-layer sincos (lanes 6..23 <- qw) ----
    const float angq = (l >= 6 && l < 24) ? qw[l - 6] : 0.f;
    float saq, caq;
    __sincosf(angq * 0.5f, &saq, &caq);
    float cQ[3][6], sQ[3][6];
    #pragma unroll
    for (int lay = 0; lay < 3; ++lay)
        #pragma unroll
        for (int q = 0; q < 6; ++q) {
            cQ[lay][q] = rl(caq, 6 + lay * 6 + q);
            sQ[lay][q] = rl(saq, 6 + lay * 6 + q);
        }

    // CNOT-ring composed permutation: new[l] = old[src]
    int src = l;
    #pragma unroll
    for (int q = 5; q >= 0; --q) {
        const int cb = 5 - q, tb = 5 - ((q + 1) % 6);
        src ^= ((src >> cb) & 1) << tb;
    }
    const int srcl = (l < 6) ? (32 >> l) : 0;   // WH result gather lane

    // ---- sim phase: 8 rows, expvals kept in qv[k] (lanes 0..5 valid) ----
    float qv[8];
    float curang = (l < 6) ? x[(size_t)w * NQ + l] : 0.f;
    #pragma unroll
    for (int k = 0; k < 8; ++k) {
        // issue next row's x-angle load; current sim hides its latency
        const float nextang = (k < 7 && l < 6)
            ? x[(size_t)(w + (k + 1) * 4096) * NQ + l] : 0.f;

        float sax, cax;
        __sincosf(curang * 0.5f, &sax, &cax);
        float cx[6], sx[6];
        #pragma unroll
        for (int i = 0; i < 6; ++i) { cx[i] = rl(cax, i); sx[i] = rl(sax, i); }

        float re = (l == 0) ? 1.f : 0.f;
        float im = 0.f;

        // encoding: RX(x[i]), RY(x[i+1]), RZ(x[i+2]) on wire i (bit 5-i)
        #pragma unroll
        for (int ww = 0; ww < 6; ++ww) {
            const int m = 1 << (5 - ww);
            const float sgn = (l & m) ? 1.f : -1.f;
            float pr = __shfl_xor(re, m), pi = __shfl_xor(im, m);
            float c = cx[ww], s = sx[ww];
            float nr = c * re + s * pi;
            float ni = c * im - s * pr;
            re = nr; im = ni;
            pr = __shfl_xor(re, m); pi = __shfl_xor(im, m);
            c = cx[(ww + 1) % 6]; s = sx[(ww + 1) % 6] * sgn;
            nr = c * re + s * pr;
            ni = c * im + s * pi;
            re = nr; im = ni;
            c = cx[(ww + 2) % 6];
            const float sg = (l & m) ? -sx[(ww + 2) % 6] : sx[(ww + 2) % 6];
            nr = c * re + sg * im;
            ni = c * im - sg * re;
            re = nr; im = ni;
        }

        // variational layers: 6x RY then CNOT ring
        #pragma unroll
        for (int lay = 0; lay < 3; ++lay) {
            #pragma unroll
            for (int q = 0; q < 6; ++q) {
                const int m = 1 << (5 - q);
                const float c = cQ[lay][q];
                const float s = sQ[lay][q];
                const float sg = (l & m) ? s : -s;
                const float pr = __shfl_xor(re, m), pi = __shfl_xor(im, m);
                const float nr = c * re + sg * pr;
                const float ni = c * im + sg * pi;
                re = nr; im = ni;
            }
            re = __shfl(re, src);
            im = __shfl(im, src);
        }

        // probabilities -> 6-stage Walsh-Hadamard; q[j] lands at lane 32>>j
        float p = re * re + im * im;
        #pragma unroll
        for (int kk = 0; kk < 6; ++kk) {
            const int m = 1 << kk;
            const float t = __shfl_xor(p, m);
            p = (l & m) ? (t - p) : (t + p);
        }
        qv[k] = __shfl(p, srcl);    // lanes 0..5 hold q0..q5 of row k
        curang = nextang;
    }

    // ---- epilogue: 4 weight chunks x 8 rows, loads-before-stores ----
    #pragma unroll
    for (int c = 0; c < 4; ++c) {
        const int cb = c * 64 + l;          // this lane's float4 column
        float4 a0, a1, a2, a3, a4, a5, bv, h0, h1;
        if (c == 0) {
            a0 = pa0; a1 = pa1; a2 = pa2; a3 = pa3; a4 = pa4; a5 = pa5;
            bv = pbv; h0 = ph0; h1 = ph1;
        } else {
            a0 = w4[cb * 6 + 0]; a1 = w4[cb * 6 + 1]; a2 = w4[cb * 6 + 2];
            a3 = w4[cb * 6 + 3]; a4 = w4[cb * 6 + 4]; a5 = w4[cb * 6 + 5];
            bv = b4[cb];
            h0 = hx4[(size_t)(w + 0 * 4096) * 256 + cb];
            h1 = hx4[(size_t)(w + 1 * 4096) * 256 + cb];
        }
        #pragma unroll
        for (int k = 0; k < 8; ++k) {
            // issue row k+2's load BEFORE row k's store (keeps vmcnt counted)
            float4 hn = {0.f, 0.f, 0.f, 0.f};
            if (k < 6) hn = hx4[(size_t)(w + (k + 2) * 4096) * 256 + cb];

            const float q0 = rl(qv[k], 0), q1 = rl(qv[k], 1), q2 = rl(qv[k], 2);
            const float q3 = rl(qv[k], 3), q4 = rl(qv[k], 4), q5 = rl(qv[k], 5);
            floatx4 res;
            res.x = h0.x + bv.x + q0*a0.x + q1*a0.y + q2*a0.z + q3*a0.w + q4*a1.x + q5*a1.y;
            res.y = h0.y + bv.y + q0*a1.z + q1*a1.w + q2*a2.x + q3*a2.y + q4*a2.z + q5*a2.w;
            res.z = h0.z + bv.z + q0*a3.x + q1*a3.y + q2*a3.z + q3*a3.w + q4*a4.x + q5*a4.y;
            res.w = h0.w + bv.w + q0*a4.z + q1*a4.w + q2*a5.x + q3*a5.y + q4*a5.z + q5*a5.w;
            __builtin_nontemporal_store(res, &out4[(size_t)(w + k * 4096) * 256 + cb]);
            h0 = h1; h1 = hn;
        }
    }
}

extern "C" void kernel_launch(void* const* d_in, const int* in_sizes, int n_in,
                              void* d_out, int out_size, void* d_ws, size_t ws_size,
                              hipStream_t stream) {
    const float* x    = (const float*)d_in[0];   // (B, 6)
    const float* hx   = (const float*)d_in[1];   // (B, H)
    const float* qw   = (const float*)d_in[2];   // (3, 6)
    const float* fc_w = (const float*)d_in[3];   // (H, 6)
    const float* fc_b = (const float*)d_in[4];   // (H,)
    float* out = (float*)d_out;

    // B = 32768, H = 1024 hardcoded in kernel geometry (4096 waves x 8 rows)
    (void)in_sizes; (void)d_ws; (void)ws_size;

    qrnn_fused_kernel<<<1024, 256, 0, stream>>>(x, hx, qw, fc_w, fc_b, out);
}